// Round 1
// baseline (30612.216 us; speedup 1.0000x reference)
//
#include <hip/hip_runtime.h>
#include <math.h>

// Problem constants
#define L_  2
#define H_  512
#define D_  512
#define B_  64
#define T_  512
#define G4  (4 * H_)   // 2048 gate rows

// State buffer layout: [dir][layer][parity][B][H]  (floats)
__device__ __forceinline__ size_t sidx(int dir, int l, int p, int b) {
    return ((((size_t)dir * L_ + l) * 2 + p) * B_ + b) * H_;
}

// ---------------------------------------------------------------------------
// Init: copy h0/c0 (L, B, 2H) into parity-1 state buffers
// ---------------------------------------------------------------------------
__global__ void init_state(const float* __restrict__ h0, const float* __restrict__ c0,
                           float* __restrict__ hbuf, float* __restrict__ cbuf) {
    int idx = blockIdx.x * blockDim.x + threadIdx.x;   // over L*B*2H = 131072
    if (idx >= L_ * B_ * 2 * H_) return;
    int h  = idx % (2 * H_);
    int b  = (idx / (2 * H_)) % B_;
    int l  = idx / (2 * H_ * B_);
    int dir = h / H_;
    int hh  = h % H_;
    hbuf[sidx(dir, l, 1, b) + hh] = h0[idx];
    cbuf[sidx(dir, l, 1, b) + hh] = c0[idx];
}

// ---------------------------------------------------------------------------
// One pipeline step: s in [0, T]. Layer 0 does t=s, layer 1 does t=s-1.
// grid = (128, 4): blockIdx.y = cell (dir*2 + layer), blockIdx.x = hc-group.
// block = 256 threads = 4 waves; wave w handles column hc = bx*4+w, lanes = batch rows.
// ---------------------------------------------------------------------------
__launch_bounds__(256)
__global__ void lstm_step(const float* __restrict__ input,
                          const float* __restrict__ Wih_f, const float* __restrict__ Whh_f,
                          const float* __restrict__ bih_f, const float* __restrict__ bhh_f,
                          const float* __restrict__ Wih_b, const float* __restrict__ Whh_b,
                          const float* __restrict__ bih_b, const float* __restrict__ bhh_b,
                          float* __restrict__ out,
                          float* __restrict__ hbuf, float* __restrict__ cbuf,
                          int s) {
    const int cell = blockIdx.y;          // 0..3
    const int dir  = cell >> 1;
    const int l    = cell & 1;
    const int t    = s - l;
    if (t < 0 || t >= T_) return;

    const int wave = threadIdx.x >> 6;    // 0..3
    const int b    = threadIdx.x & 63;    // batch row (lane)
    int hc = blockIdx.x * 4 + wave;       // 0..511 output column
    hc = __builtin_amdgcn_readfirstlane(hc);

    const float* Wih = (dir ? Wih_b : Wih_f) + (size_t)l * G4 * D_;
    const float* Whh = (dir ? Whh_b : Whh_f) + (size_t)l * G4 * H_;
    const float* bih = (dir ? bih_b : bih_f) + l * G4;
    const float* bhh = (dir ? bhh_b : bhh_f) + l * G4;

    const int tx = dir ? (T_ - 1 - t) : t;    // time index into input & out

    // x source: layer 0 reads input[:, tx, :]; layer 1 reads layer-0 h at time t
    const float* xsrc;
    size_t xstride;
    if (l == 0) { xsrc = input + (size_t)tx * D_; xstride = (size_t)T_ * D_; }
    else        { xsrc = hbuf + sidx(dir, 0, t & 1, 0); xstride = H_; }

    const float* hprev = hbuf + sidx(dir, l, (t + 1) & 1, 0);   // row stride H_

    __shared__ float lds[64][132];   // one [64][128] chunk, padded (132*4B = 33*16B)

    float4 acc4[4];
    #pragma unroll
    for (int q = 0; q < 4; q++) acc4[q] = make_float4(0.f, 0.f, 0.f, 0.f);

    // 8 chunks of K=128: first 4 over x (Wih), last 4 over h (Whh)
    for (int ch = 0; ch < 8; ++ch) {
        const bool  isx = (ch < 4);
        const int   k0  = (isx ? ch : ch - 4) * 128;
        const float* src     = isx ? xsrc : hprev;
        const size_t rstride = isx ? xstride : (size_t)H_;
        const float* W       = isx ? Wih : Whh;

        __syncthreads();
        {   // cooperative load: 64 rows x 128 k = 2048 float4, 8 per thread
            const int kk4 = threadIdx.x & 31;       // 0..31
            const int r0  = threadIdx.x >> 5;       // 0..7
            #pragma unroll
            for (int it = 0; it < 8; ++it) {
                const int r = r0 + it * 8;
                float4 v = *reinterpret_cast<const float4*>(src + (size_t)r * rstride + k0 + kk4 * 4);
                *reinterpret_cast<float4*>(&lds[r][kk4 * 4]) = v;
            }
        }
        __syncthreads();

        #pragma unroll 4
        for (int kk4 = 0; kk4 < 32; ++kk4) {
            float4 xv = *reinterpret_cast<const float4*>(&lds[b][kk4 * 4]);
            #pragma unroll
            for (int q = 0; q < 4; q++) {
                const float* Wr = W + (size_t)(q * H_ + hc) * 512 + k0;
                float4 wv = *reinterpret_cast<const float4*>(Wr + kk4 * 4);
                acc4[q].x += xv.x * wv.x;
                acc4[q].y += xv.y * wv.y;
                acc4[q].z += xv.z * wv.z;
                acc4[q].w += xv.w * wv.w;
            }
        }
    }

    float g[4];
    #pragma unroll
    for (int q = 0; q < 4; q++) {
        const int row = q * H_ + hc;
        g[q] = bih[row] + bhh[row] + acc4[q].x + acc4[q].y + acc4[q].z + acc4[q].w;
    }

    const float zi = g[0], zf = g[1], zg = g[2], zo = g[3];
    const float cprev = cbuf[sidx(dir, l, (t + 1) & 1, b) + hc];
    const float si = 1.f / (1.f + expf(-zi));
    const float sf = 1.f / (1.f + expf(-zf));
    const float so = 1.f / (1.f + expf(-zo));
    const float tg = tanhf(zg);
    const float cn = sf * cprev + si * tg;
    const float hn = so * tanhf(cn);

    hbuf[sidx(dir, l, t & 1, b) + hc] = hn;
    cbuf[sidx(dir, l, t & 1, b) + hc] = cn;
    if (l == 1)
        out[((size_t)b * T_ + tx) * (2 * H_) + dir * H_ + hc] = hn;
}

// ---------------------------------------------------------------------------
// Final: write h, c outputs (both live in parity-1 buffers since (T-1)&1 == 1)
// ---------------------------------------------------------------------------
__global__ void write_final(const float* __restrict__ hbuf, const float* __restrict__ cbuf,
                            float* __restrict__ out) {
    int idx = blockIdx.x * blockDim.x + threadIdx.x;   // over L*B*2H
    if (idx >= L_ * B_ * 2 * H_) return;
    int h  = idx % (2 * H_);
    int b  = (idx / (2 * H_)) % B_;
    int l  = idx / (2 * H_ * B_);
    int dir = h / H_;
    int hh  = h % H_;
    float* hout = out + (size_t)B_ * T_ * 2 * H_;
    float* cout = hout + (size_t)L_ * B_ * 2 * H_;
    hout[idx] = hbuf[sidx(dir, l, 1, b) + hh];
    cout[idx] = cbuf[sidx(dir, l, 1, b) + hh];
}

// ---------------------------------------------------------------------------
extern "C" void kernel_launch(void* const* d_in, const int* in_sizes, int n_in,
                              void* d_out, int out_size, void* d_ws, size_t ws_size,
                              hipStream_t stream) {
    const float* input = (const float*)d_in[0];
    const float* h0    = (const float*)d_in[1];
    const float* c0    = (const float*)d_in[2];
    const float* Wih_f = (const float*)d_in[3];
    const float* Whh_f = (const float*)d_in[4];
    const float* bih_f = (const float*)d_in[5];
    const float* bhh_f = (const float*)d_in[6];
    const float* Wih_b = (const float*)d_in[7];
    const float* Whh_b = (const float*)d_in[8];
    const float* bih_b = (const float*)d_in[9];
    const float* bhh_b = (const float*)d_in[10];
    float* out  = (float*)d_out;
    float* hbuf = (float*)d_ws;                        // 524288 floats (2 MB)
    float* cbuf = hbuf + (size_t)2 * L_ * 2 * B_ * H_; // another 524288 floats

    init_state<<<dim3(512), 256, 0, stream>>>(h0, c0, hbuf, cbuf);
    for (int s = 0; s <= T_; ++s) {
        lstm_step<<<dim3(128, 4), 256, 0, stream>>>(input,
            Wih_f, Whh_f, bih_f, bhh_f, Wih_b, Whh_b, bih_b, bhh_b,
            out, hbuf, cbuf, s);
    }
    write_final<<<dim3(512), 256, 0, stream>>>(hbuf, cbuf, out);
}

// Round 2
// 3905.527 us; speedup vs baseline: 7.8382x; 7.8382x over previous
//
#include <hip/hip_runtime.h>
#include <hip/hip_bf16.h>
#include <math.h>

#define L_  2
#define H_  512
#define D_  512
#define B_  64
#define T_  512

typedef __attribute__((ext_vector_type(8))) __bf16  bf16x8;
typedef __attribute__((ext_vector_type(4))) float   f32x4;

union FragU { uint4 u; bf16x8 v; };

// ---- workspace layout (byte offsets) --------------------------------------
// Wp       : bf16  [4][32][4][32][64][8]  = 16,777,216 B   (packed weights)
// input_tb : bf16  [512][64][512]         = 33,554,432 B   (input transposed)
// h_bf     : bf16  [2][2][2][64][512]     =    524,288 B   (dir,layer,parity)
// c_f32    : f32   [4][64][512]           =    524,288 B
// h_f32    : f32   [4][64][512]           =    524,288 B
// bias_sum : f32   [4][2048]              =     32,768 B
#define OFF_WP    0
#define OFF_INTB  (16777216)
#define OFF_HBF   (16777216 + 33554432)
#define OFF_CF32  (OFF_HBF + 524288)
#define OFF_HF32  (OFF_CF32 + 524288)
#define OFF_BIAS  (OFF_HF32 + 524288)

__device__ __forceinline__ int hoff(int dir, int lay, int par) {
    return (((dir * 2 + lay) * 2 + par)) * (B_ * H_);   // in bf16 elements
}

// ---------------------------------------------------------------------------
// Pack weights into MFMA fragment order, bf16.
// Wp[((((cell*32+hct)*4+g)*32+ks)*64+l)*8 + j] =
//   W[cell][g*512 + hct*16 + (l&15)][ks*32 + (l>>4)*8 + j]
// where W = [Wih | Whh] along k (k<512 -> Wih).
// One thread per fragment chunk (8 elems): tid == linear frag index.
// ---------------------------------------------------------------------------
__global__ void prep_weights(const float* __restrict__ Wih_f, const float* __restrict__ Whh_f,
                             const float* __restrict__ Wih_b, const float* __restrict__ Whh_b,
                             __hip_bfloat16* __restrict__ Wp) {
    int tid = blockIdx.x * blockDim.x + threadIdx.x;     // 0 .. 1048575
    int l    = tid & 63;
    int g    = (tid >> 11) & 3;
    int hct  = (tid >> 13) & 31;
    int cell = tid >> 18;
    int dir  = cell >> 1, lay = cell & 1;
    int ks   = (tid >> 6) & 31;

    const float* Wih = (dir ? Wih_b : Wih_f) + (size_t)lay * 2048 * 512;
    const float* Whh = (dir ? Whh_b : Whh_f) + (size_t)lay * 2048 * 512;

    int n     = hct * 16 + (l & 15);
    int grow  = g * 512 + n;
    int kbase = ks * 32 + ((l >> 4) * 8);
    const float* src = (kbase < 512) ? (Wih + (size_t)grow * 512 + kbase)
                                     : (Whh + (size_t)grow * 512 + (kbase - 512));
    __hip_bfloat16 tmp[8];
    #pragma unroll
    for (int j = 0; j < 8; ++j) tmp[j] = __float2bfloat16(src[j]);
    *reinterpret_cast<uint4*>(Wp + (size_t)tid * 8) = *reinterpret_cast<uint4*>(tmp);
}

// ---------------------------------------------------------------------------
// input [b][t][d] fp32 -> input_tb [t][b][d] bf16
// ---------------------------------------------------------------------------
__global__ void prep_input(const float* __restrict__ input, __hip_bfloat16* __restrict__ itb) {
    int tid = blockIdx.x * blockDim.x + threadIdx.x;     // 0 .. 2097151
    int dc  = tid & 63;
    int b   = (tid >> 6) & 63;
    int tau = tid >> 12;
    const float* src = input + ((size_t)b * T_ + tau) * D_ + dc * 8;
    __hip_bfloat16 tmp[8];
    #pragma unroll
    for (int j = 0; j < 8; ++j) tmp[j] = __float2bfloat16(src[j]);
    *reinterpret_cast<uint4*>(itb + ((size_t)tau * B_ + b) * D_ + dc * 8) =
        *reinterpret_cast<uint4*>(tmp);
}

// ---------------------------------------------------------------------------
// Init h_bf (parity 1) and c_f32 from h0/c0; bias_sum = bih + bhh.
// ---------------------------------------------------------------------------
__global__ void prep_misc(const float* __restrict__ h0, const float* __restrict__ c0,
                          const float* __restrict__ bih_f, const float* __restrict__ bhh_f,
                          const float* __restrict__ bih_b, const float* __restrict__ bhh_b,
                          __hip_bfloat16* __restrict__ h_bf, float* __restrict__ c_f32,
                          float* __restrict__ bias_sum) {
    int idx = blockIdx.x * blockDim.x + threadIdx.x;
    if (idx < 131072) {            // L*B*2H state init
        int hh2 = idx & 1023;
        int b   = (idx >> 10) & 63;
        int l   = idx >> 16;
        int dir = hh2 >> 9, hh = hh2 & 511;
        h_bf[hoff(dir, l, 1) + b * H_ + hh] = __float2bfloat16(h0[idx]);
        c_f32[(((size_t)(dir * 2 + l)) * B_ + b) * H_ + hh] = c0[idx];
    } else if (idx < 131072 + 8192) {
        int i2   = idx - 131072;
        int cell = i2 >> 11, row = i2 & 2047;
        int dir  = cell >> 1, lay = cell & 1;
        const float* bi = (dir ? bih_b : bih_f) + lay * 2048;
        const float* bh = (dir ? bhh_b : bhh_f) + lay * 2048;
        bias_sum[i2] = bi[row] + bh[row];
    }
}

// ---------------------------------------------------------------------------
// One pipeline step s in [0,T]. layer0: t=s, layer1: t=s-1.
// grid 512 blocks x 256 thr. bid = mblk*128 + (cell*32 + hcblk):
//   same weight panel (cell,hcblk) for all 4 mblk -> same XCD (bid%8 equal).
// Wave g (=tid>>6) computes gate g for (16 m-rows, 16 hc-cols), K=1024.
// ---------------------------------------------------------------------------
__launch_bounds__(256, 2)
__global__ void lstm_step(const __hip_bfloat16* __restrict__ Wp,
                          const __hip_bfloat16* __restrict__ itb,
                          __hip_bfloat16* __restrict__ h_bf,
                          float* __restrict__ c_f32, float* __restrict__ h_f32,
                          const float* __restrict__ bias_sum,
                          float* __restrict__ out, int s) {
    const int bid    = blockIdx.x;
    const int mblk   = bid >> 7;
    const int cellhc = bid & 127;
    const int cell   = cellhc >> 5;
    const int hcblk  = cellhc & 31;
    const int dir    = cell >> 1, lay = cell & 1;
    const int t      = s - lay;
    if (t < 0 || t >= T_) return;
    const int tx = dir ? (T_ - 1 - t) : t;

    const __hip_bfloat16* src_x = lay ? (h_bf + hoff(dir, 0, t & 1))
                                      : (itb + (size_t)tx * B_ * D_);
    const __hip_bfloat16* src_h = h_bf + hoff(dir, lay, (t + 1) & 1);

    __shared__ uint4 ldsA[2048];          // 32 ksteps x 64 lanes x 16B = 32 KB
    __shared__ float ldsG[4][16][16];     // gates staging, 4 KB

    const int tid = threadIdx.x;

    // cooperative A-fragment staging (rows mblk*16..+15, K=1024)
    #pragma unroll
    for (int it = 0; it < 8; ++it) {
        int c   = tid + it * 256;
        int ks  = c >> 6, l = c & 63;
        int row = mblk * 16 + (l & 15);
        int k   = ks * 32 + ((l >> 4) * 8);
        const __hip_bfloat16* p = (k < 512) ? (src_x + (size_t)row * 512 + k)
                                            : (src_h + (size_t)row * 512 + (k - 512));
        ldsA[c] = *reinterpret_cast<const uint4*>(p);
    }
    __syncthreads();

    const int g = tid >> 6, lane = tid & 63;
    const uint4* wp = reinterpret_cast<const uint4*>(Wp) +
                      ((size_t)cellhc * 4 + g) * 2048 + lane;
    const uint4* ap = ldsA + lane;

    f32x4 acc = {0.f, 0.f, 0.f, 0.f};
    #pragma unroll 8
    for (int ks = 0; ks < 32; ++ks) {
        FragU a, b;
        a.u = ap[ks * 64];
        b.u = wp[ks * 64];
        acc = __builtin_amdgcn_mfma_f32_16x16x32_bf16(a.v, b.v, acc, 0, 0, 0);
    }

    const int hcl = lane & 15;
    const float bsum = bias_sum[cell * 2048 + g * 512 + hcblk * 16 + hcl];
    #pragma unroll
    for (int r = 0; r < 4; ++r)
        ldsG[g][(lane >> 4) * 4 + r][hcl] = acc[r] + bsum;
    __syncthreads();

    // pointwise LSTM cell: one (m, hc) element per thread
    const int m = tid >> 4, hl = tid & 15;
    const float gi = ldsG[0][m][hl];
    const float gf = ldsG[1][m][hl];
    const float gg = ldsG[2][m][hl];
    const float go = ldsG[3][m][hl];
    const int b  = mblk * 16 + m;
    const int hc = hcblk * 16 + hl;
    const size_t ci = ((size_t)cell * B_ + b) * H_ + hc;

    const float cprev = c_f32[ci];
    const float si = 1.f / (1.f + expf(-gi));
    const float sf = 1.f / (1.f + expf(-gf));
    const float so = 1.f / (1.f + expf(-go));
    const float cn = sf * cprev + si * tanhf(gg);
    const float hn = so * tanhf(cn);

    c_f32[ci] = cn;
    h_f32[ci] = hn;
    h_bf[hoff(dir, lay, t & 1) + b * H_ + hc] = __float2bfloat16(hn);
    if (lay)
        out[((size_t)b * T_ + tx) * (2 * H_) + dir * H_ + hc] = hn;
}

// ---------------------------------------------------------------------------
__global__ void final_write(const float* __restrict__ h_f32, const float* __restrict__ c_f32,
                            float* __restrict__ out) {
    int idx = blockIdx.x * blockDim.x + threadIdx.x;   // over L*B*2H = 131072
    if (idx >= 131072) return;
    int hh2 = idx & 1023;
    int b   = (idx >> 10) & 63;
    int l   = idx >> 16;
    int dir = hh2 >> 9, hh = hh2 & 511;
    size_t ci = (((size_t)(dir * 2 + l)) * B_ + b) * H_ + hh;
    float* hout = out + (size_t)B_ * T_ * 2 * H_;
    float* cout = hout + (size_t)L_ * B_ * 2 * H_;
    hout[idx] = h_f32[ci];
    cout[idx] = c_f32[ci];
}

// ---------------------------------------------------------------------------
extern "C" void kernel_launch(void* const* d_in, const int* in_sizes, int n_in,
                              void* d_out, int out_size, void* d_ws, size_t ws_size,
                              hipStream_t stream) {
    const float* input = (const float*)d_in[0];
    const float* h0    = (const float*)d_in[1];
    const float* c0    = (const float*)d_in[2];
    const float* Wih_f = (const float*)d_in[3];
    const float* Whh_f = (const float*)d_in[4];
    const float* bih_f = (const float*)d_in[5];
    const float* bhh_f = (const float*)d_in[6];
    const float* Wih_b = (const float*)d_in[7];
    const float* Whh_b = (const float*)d_in[8];
    const float* bih_b = (const float*)d_in[9];
    const float* bhh_b = (const float*)d_in[10];
    float* out = (float*)d_out;

    char* ws = (char*)d_ws;
    __hip_bfloat16* Wp   = (__hip_bfloat16*)(ws + OFF_WP);
    __hip_bfloat16* itb  = (__hip_bfloat16*)(ws + OFF_INTB);
    __hip_bfloat16* h_bf = (__hip_bfloat16*)(ws + OFF_HBF);
    float* c_f32    = (float*)(ws + OFF_CF32);
    float* h_f32    = (float*)(ws + OFF_HF32);
    float* bias_sum = (float*)(ws + OFF_BIAS);

    prep_weights<<<4096, 256, 0, stream>>>(Wih_f, Whh_f, Wih_b, Whh_b, Wp);
    prep_input  <<<8192, 256, 0, stream>>>(input, itb);
    prep_misc   <<<544, 256, 0, stream>>>(h0, c0, bih_f, bhh_f, bih_b, bhh_b,
                                          h_bf, c_f32, bias_sum);
    for (int s = 0; s <= T_; ++s)
        lstm_step<<<512, 256, 0, stream>>>(Wp, itb, h_bf, c_f32, h_f32,
                                           bias_sum, out, s);
    final_write<<<512, 256, 0, stream>>>(h_f32, c_f32, out);
}